// Round 1
// 636.953 us; speedup vs baseline: 1.0350x; 1.0350x over previous
//
#include <hip/hip_runtime.h>
#include <cstddef>

// Problem constants (reference: B=32, NDOC=4, L=512, E=512)
#define BATCH 32
#define NB    128
#define LL    512
#define EE    512
#define SCALE 0.044194173824159216f
#define NEG_INF -1e9f

typedef __attribute__((ext_vector_type(4))) float f32x4;
typedef __attribute__((ext_vector_type(8))) short s16x8;          // 8 bf16 (4 VGPRs) MFMA frag
typedef __attribute__((ext_vector_type(4))) unsigned short u16x4;

__device__ __forceinline__ unsigned short f2b(float f) {          // f32 -> bf16 RNE
    unsigned u = __float_as_uint(f);
    u += 0x7FFFu + ((u >> 16) & 1u);
    return (unsigned short)(u >> 16);
}
__device__ __forceinline__ float b2f(unsigned short h) {
    return __uint_as_float(((unsigned)h) << 16);
}

// async global->LDS, 16B per lane. LDS dest = wave-uniform base + lane*16.
__device__ __forceinline__ void gld_lds16(const unsigned short* g, unsigned short* l) {
    __builtin_amdgcn_global_load_lds(
        (const __attribute__((address_space(1))) void*)g,
        (__attribute__((address_space(3))) void*)l, 16, 0, 0);
}

// ---------------------------------------------------------------------------
// Converters: x1 -> bf16; x2 -> bf16 (row) + bf16 transposed; fw -> fw^T bf16
// ---------------------------------------------------------------------------
__global__ __launch_bounds__(256) void k_cvt_x1(
    const float* __restrict__ x1, unsigned short* __restrict__ x1bf)
{
    const size_t idx = (size_t)blockIdx.x * 256 + threadIdx.x;
    f32x4 v = *(const f32x4*)(x1 + idx * 4);
    u16x4 o = { f2b(v[0]), f2b(v[1]), f2b(v[2]), f2b(v[3]) };
    *(u16x4*)(x1bf + idx * 4) = o;
}

__global__ __launch_bounds__(256) void k_cvt_x2(
    const float* __restrict__ x2,
    unsigned short* __restrict__ x2bf, unsigned short* __restrict__ x2t)
{
    __shared__ float T[64][65];
    const int i = blockIdx.z, kb = blockIdx.y * 64, eb = blockIdx.x * 64;
    const float* src = x2 + (size_t)i * LL * EE;
    unsigned short* db = x2bf + (size_t)i * LL * EE;
    unsigned short* dt = x2t  + (size_t)i * LL * EE;
    const int t = threadIdx.x, r16 = t >> 4, c4 = (t & 15) * 4;
#pragma unroll
    for (int p = 0; p < 4; ++p) {
        int row = p * 16 + r16;
        f32x4 v = *(const f32x4*)(src + (size_t)(kb + row) * EE + eb + c4);
        T[row][c4] = v[0]; T[row][c4+1] = v[1]; T[row][c4+2] = v[2]; T[row][c4+3] = v[3];
        u16x4 o = { f2b(v[0]), f2b(v[1]), f2b(v[2]), f2b(v[3]) };
        *(u16x4*)(db + (size_t)(kb + row) * EE + eb + c4) = o;
    }
    __syncthreads();
#pragma unroll
    for (int p = 0; p < 4; ++p) {
        int erow = p * 16 + r16;
        u16x4 o = { f2b(T[c4][erow]), f2b(T[c4+1][erow]),
                    f2b(T[c4+2][erow]), f2b(T[c4+3][erow]) };
        *(u16x4*)(dt + (size_t)(eb + erow) * LL + kb + c4) = o;   // dt[e][k]=src[k][e]
    }
}

// fw [1024][512] -> fwt[e][j'] bf16 with K-interleave j' = (j<512) ? 2j : 2(j-512)+1
// (matches Cbuf's interleaved [diff,prod] pair layout; GEMM result invariant).
__global__ __launch_bounds__(256) void k_cvt_fw(
    const float* __restrict__ fw, unsigned short* __restrict__ fwt)
{
    __shared__ float T[64][65];
    const int jb = blockIdx.y * 64, eb = blockIdx.x * 64;
    const int t = threadIdx.x, r16 = t >> 4, c4 = (t & 15) * 4;
#pragma unroll
    for (int p = 0; p < 4; ++p) {
        int row = p * 16 + r16;
        f32x4 v = *(const f32x4*)(fw + (size_t)(jb + row) * EE + eb + c4);
        T[row][c4] = v[0]; T[row][c4+1] = v[1]; T[row][c4+2] = v[2]; T[row][c4+3] = v[3];
    }
    __syncthreads();
#pragma unroll
    for (int p = 0; p < 4; ++p) {
        int erow = p * 16 + r16;
#pragma unroll
        for (int k = 0; k < 4; ++k) {
            int jold = jb + c4 + k;
            int jn = (jold < 512) ? (2 * jold) : (2 * (jold - 512) + 1);
            fwt[(size_t)(eb + erow) * 1024 + jn] = f2b(T[c4 + k][erow]);
        }
    }
}

// ---------------------------------------------------------------------------
// K1: scores = mask(x1 @ x2^T * scale). bf16 MFMA, 128x128 tile, BK=32,
// m97-style global_load_lds staging (linear LDS, no VGPR round-trip).
// ---------------------------------------------------------------------------
__global__ __launch_bounds__(256) void k_scores_mfma(
    const unsigned short* __restrict__ x1bf,
    const unsigned short* __restrict__ x2bf,
    const int* __restrict__ x1_len, const int* __restrict__ x2_len,
    float* __restrict__ attn)
{
    __shared__ unsigned short Al[128 * 32];
    __shared__ unsigned short Bl[128 * 32];
    const int i  = blockIdx.x;
    const int q0 = (blockIdx.y >> 2) * 128;
    const int k0 = (blockIdx.y & 3) * 128;
    const unsigned short* Ag = x1bf + (size_t)(i & 31) * LL * EE;
    const unsigned short* Bg = x2bf + (size_t)i * LL * EE;
    const int t = threadIdx.x, lane = t & 63;
    const int w = t >> 6, wrow = w >> 1, wcol = w & 1;
    const int m = lane & 15, quad = lane >> 4;
    const int lrow = lane >> 2, lcol = (lane & 3) * 8;   // staging lane mapping

    f32x4 acc[4][4];
#pragma unroll
    for (int r = 0; r < 4; ++r)
#pragma unroll
        for (int c = 0; c < 4; ++c) acc[r][c] = (f32x4){0.f, 0.f, 0.f, 0.f};

    for (int e0 = 0; e0 < EE; e0 += 32) {
#pragma unroll
        for (int c = 0; c < 2; ++c) {
            const int s = c * 4 + w;                      // segment: 16 rows
            gld_lds16(Ag + (size_t)(q0 + s * 16 + lrow) * EE + e0 + lcol, &Al[s * 512]);
            gld_lds16(Bg + (size_t)(k0 + s * 16 + lrow) * EE + e0 + lcol, &Bl[s * 512]);
        }
        __syncthreads();                                  // drains vmcnt -> LDS valid
        s16x8 af[4], bfr[4];
#pragma unroll
        for (int rt = 0; rt < 4; ++rt)
            af[rt] = *(const s16x8*)&Al[(wrow * 64 + rt * 16 + m) * 32 + quad * 8];
#pragma unroll
        for (int ct = 0; ct < 4; ++ct)
            bfr[ct] = *(const s16x8*)&Bl[(wcol * 64 + ct * 16 + m) * 32 + quad * 8];
#pragma unroll
        for (int rt = 0; rt < 4; ++rt)
#pragma unroll
            for (int ct = 0; ct < 4; ++ct)
                acc[rt][ct] = __builtin_amdgcn_mfma_f32_16x16x32_bf16(
                    af[rt], bfr[ct], acc[rt][ct], 0, 0, 0);
        __syncthreads();                                  // all reads done before restage
    }

    const int qlen = x1_len[i & 31];
    const int klen = x2_len[i];
    float* op = attn + (size_t)i * LL * LL;
#pragma unroll
    for (int rt = 0; rt < 4; ++rt) {
#pragma unroll
        for (int reg = 0; reg < 4; ++reg) {
            const int q = q0 + wrow * 64 + rt * 16 + quad * 4 + reg;
            const bool qok = q < qlen;
#pragma unroll
            for (int ct = 0; ct < 4; ++ct) {
                const int k = k0 + wcol * 64 + ct * 16 + m;
                float v = (qok && k < klen) ? acc[rt][ct][reg] * SCALE : NEG_INF;
                op[(size_t)q * LL + k] = v;
            }
        }
    }
}

// ---------------------------------------------------------------------------
// K2: in-place row softmax; also emits a bf16 copy for the PV GEMM.
// ---------------------------------------------------------------------------
__global__ __launch_bounds__(256) void k_softmax(
    float* __restrict__ attn, unsigned short* __restrict__ attnbf)
{
    const int row  = blockIdx.x * 4 + (threadIdx.x >> 6);
    const int lane = threadIdx.x & 63;
    float* p = attn + (size_t)row * LL + lane * 8;
    float4 v0 = *(float4*)p;
    float4 v1 = *(float4*)(p + 4);
    float mx = fmaxf(fmaxf(fmaxf(v0.x, v0.y), fmaxf(v0.z, v0.w)),
                     fmaxf(fmaxf(v1.x, v1.y), fmaxf(v1.z, v1.w)));
#pragma unroll
    for (int o = 32; o > 0; o >>= 1) mx = fmaxf(mx, __shfl_xor(mx, o));
    v0.x = __expf(v0.x - mx); v0.y = __expf(v0.y - mx);
    v0.z = __expf(v0.z - mx); v0.w = __expf(v0.w - mx);
    v1.x = __expf(v1.x - mx); v1.y = __expf(v1.y - mx);
    v1.z = __expf(v1.z - mx); v1.w = __expf(v1.w - mx);
    float s = v0.x + v0.y + v0.z + v0.w + v1.x + v1.y + v1.z + v1.w;
#pragma unroll
    for (int o = 32; o > 0; o >>= 1) s += __shfl_xor(s, o);
    const float inv = 1.0f / s;
    v0.x *= inv; v0.y *= inv; v0.z *= inv; v0.w *= inv;
    v1.x *= inv; v1.y *= inv; v1.z *= inv; v1.w *= inv;
    *(float4*)p = v0;
    *(float4*)(p + 4) = v1;
    unsigned short* pb = attnbf + (size_t)row * LL + lane * 8;
    u16x4 o0 = { f2b(v0.x), f2b(v0.y), f2b(v0.z), f2b(v0.w) };
    u16x4 o1 = { f2b(v1.x), f2b(v1.y), f2b(v1.z), f2b(v1.w) };
    *(u16x4*)pb       = o0;
    *(u16x4*)(pb + 4) = o1;
}

// ---------------------------------------------------------------------------
// K3: x1_att = attn @ x2 (A = bf16 attnbf; B = x2^T). global_load_lds staging.
// Epilogue: Cbuf[l][2e+0]=x1-att, Cbuf[l][2e+1]=x1*att (interleaved pair ->
// one coalesced 4B store per element instead of two 2B stores 1KB apart).
// ---------------------------------------------------------------------------
__global__ __launch_bounds__(256) void k_pv_mfma(
    const unsigned short* __restrict__ attnbf,
    const unsigned short* __restrict__ x2t,
    const unsigned short* __restrict__ x1bf,
    unsigned short* __restrict__ Cbuf)
{
    __shared__ unsigned short Al[128 * 32];
    __shared__ unsigned short Bl[128 * 32];
    const int i  = blockIdx.x;
    const int q0 = (blockIdx.y >> 2) * 128;   // l rows
    const int e0 = (blockIdx.y & 3) * 128;    // e cols
    const unsigned short* Ag = attnbf + (size_t)i * LL * LL;
    const unsigned short* Bg = x2t   + (size_t)i * LL * EE;
    const int t = threadIdx.x, lane = t & 63;
    const int w = t >> 6, wrow = w >> 1, wcol = w & 1;
    const int m = lane & 15, quad = lane >> 4;
    const int lrow = lane >> 2, lcol = (lane & 3) * 8;

    f32x4 acc[4][4];
#pragma unroll
    for (int r = 0; r < 4; ++r)
#pragma unroll
        for (int c = 0; c < 4; ++c) acc[r][c] = (f32x4){0.f, 0.f, 0.f, 0.f};

    for (int kk0 = 0; kk0 < LL; kk0 += 32) {
#pragma unroll
        for (int c = 0; c < 2; ++c) {
            const int s = c * 4 + w;
            gld_lds16(Ag + (size_t)(q0 + s * 16 + lrow) * LL + kk0 + lcol, &Al[s * 512]);
            gld_lds16(Bg + (size_t)(e0 + s * 16 + lrow) * LL + kk0 + lcol, &Bl[s * 512]);
        }
        __syncthreads();
        s16x8 af[4], bfr[4];
#pragma unroll
        for (int rt = 0; rt < 4; ++rt)
            af[rt] = *(const s16x8*)&Al[(wrow * 64 + rt * 16 + m) * 32 + quad * 8];
#pragma unroll
        for (int ct = 0; ct < 4; ++ct)
            bfr[ct] = *(const s16x8*)&Bl[(wcol * 64 + ct * 16 + m) * 32 + quad * 8];
#pragma unroll
        for (int rt = 0; rt < 4; ++rt)
#pragma unroll
            for (int ct = 0; ct < 4; ++ct)
                acc[rt][ct] = __builtin_amdgcn_mfma_f32_16x16x32_bf16(
                    af[rt], bfr[ct], acc[rt][ct], 0, 0, 0);
        __syncthreads();
    }

    const unsigned short* x1p = x1bf + (size_t)(i & 31) * LL * EE;
    unsigned short* Cb = Cbuf + (size_t)i * LL * 1024;
#pragma unroll
    for (int rt = 0; rt < 4; ++rt) {
#pragma unroll
        for (int reg = 0; reg < 4; ++reg) {
            const int l = q0 + wrow * 64 + rt * 16 + quad * 4 + reg;
#pragma unroll
            for (int ct = 0; ct < 4; ++ct) {
                const int e = e0 + wcol * 64 + ct * 16 + m;
                float att = acc[rt][ct][reg];
                float xv  = b2f(x1p[(size_t)l * EE + e]);
                unsigned pr = (unsigned)f2b(xv - att) | ((unsigned)f2b(xv * att) << 16);
                *(unsigned*)(Cb + (size_t)l * 1024 + 2 * e) = pr;
            }
        }
    }
}

// ---------------------------------------------------------------------------
// K4: fus = relu(Cbuf @ fw + b) with per-l-tile mean/max pooling partials.
// A rows are the interleaved Cbuf layout; B (fwt) carries the same K-perm.
// ---------------------------------------------------------------------------
__global__ __launch_bounds__(256) void k_fuse_mfma(
    const unsigned short* __restrict__ Cbuf,
    const unsigned short* __restrict__ fwt,
    const float* __restrict__ fb,
    float* __restrict__ pmean, float* __restrict__ pmax)
{
    __shared__ unsigned short Al[128 * 32];
    __shared__ unsigned short Bl[128 * 32];
    __shared__ float psum[2][128];
    __shared__ float pmx[2][128];
    const int i  = blockIdx.x;
    const int lt = blockIdx.y >> 2;
    const int e0 = (blockIdx.y & 3) * 128;
    const unsigned short* Ab = Cbuf + ((size_t)i * LL + lt * 128) * 1024;
    const int t = threadIdx.x, lane = t & 63;
    const int w = t >> 6, wrow = w >> 1, wcol = w & 1;
    const int m = lane & 15, quad = lane >> 4;
    const int lrow = lane >> 2, lcol = (lane & 3) * 8;

    float bias[4];
#pragma unroll
    for (int ct = 0; ct < 4; ++ct) bias[ct] = fb[e0 + wcol * 64 + ct * 16 + m];
    float csum[4] = {0.f, 0.f, 0.f, 0.f};
    float cmax[4] = {-3e38f, -3e38f, -3e38f, -3e38f};

    f32x4 acc[4][4];
#pragma unroll
    for (int r = 0; r < 4; ++r)
#pragma unroll
        for (int c = 0; c < 4; ++c) acc[r][c] = (f32x4){0.f, 0.f, 0.f, 0.f};

    for (int j0 = 0; j0 < 1024; j0 += 32) {
#pragma unroll
        for (int c = 0; c < 2; ++c) {
            const int s = c * 4 + w;
            gld_lds16(Ab + (size_t)(s * 16 + lrow) * 1024 + j0 + lcol, &Al[s * 512]);
            gld_lds16(fwt + (size_t)(e0 + s * 16 + lrow) * 1024 + j0 + lcol, &Bl[s * 512]);
        }
        __syncthreads();
        s16x8 af[4], bfr[4];
#pragma unroll
        for (int rt = 0; rt < 4; ++rt)
            af[rt] = *(const s16x8*)&Al[(wrow * 64 + rt * 16 + m) * 32 + quad * 8];
#pragma unroll
        for (int ct = 0; ct < 4; ++ct)
            bfr[ct] = *(const s16x8*)&Bl[(wcol * 64 + ct * 16 + m) * 32 + quad * 8];
#pragma unroll
        for (int rt = 0; rt < 4; ++rt)
#pragma unroll
            for (int ct = 0; ct < 4; ++ct)
                acc[rt][ct] = __builtin_amdgcn_mfma_f32_16x16x32_bf16(
                    af[rt], bfr[ct], acc[rt][ct], 0, 0, 0);
        __syncthreads();
    }
#pragma unroll
    for (int rt = 0; rt < 4; ++rt)
#pragma unroll
        for (int reg = 0; reg < 4; ++reg)
#pragma unroll
            for (int ct = 0; ct < 4; ++ct) {
                float f = fmaxf(acc[rt][ct][reg] + bias[ct], 0.f);
                csum[ct] += f;
                cmax[ct] = fmaxf(cmax[ct], f);
            }
#pragma unroll
    for (int ct = 0; ct < 4; ++ct) {
        csum[ct] += __shfl_xor(csum[ct], 16);
        csum[ct] += __shfl_xor(csum[ct], 32);
        cmax[ct] = fmaxf(cmax[ct], __shfl_xor(cmax[ct], 16));
        cmax[ct] = fmaxf(cmax[ct], __shfl_xor(cmax[ct], 32));
    }
    if (quad == 0) {
#pragma unroll
        for (int ct = 0; ct < 4; ++ct) {
            psum[wrow][wcol * 64 + ct * 16 + m] = csum[ct];
            pmx[wrow][wcol * 64 + ct * 16 + m] = cmax[ct];
        }
    }
    __syncthreads();
    if (t < 128) {
        float s  = psum[0][t] + psum[1][t];
        float mx = fmaxf(pmx[0][t], pmx[1][t]);
        pmean[((size_t)i * 4 + lt) * EE + e0 + t] = s;     // raw sum over 128 l's
        pmax[((size_t)i * 4 + lt) * EE + e0 + t]  = mx;
    }
}

// ---------------------------------------------------------------------------
// K5a: split-K partial GEMM for the output head; reduces the 4 l-tile pooling
// partials inline while loading the pooled vector.
// ---------------------------------------------------------------------------
__global__ __launch_bounds__(256) void k_out_split(
    const float* __restrict__ pmean, const float* __restrict__ pmax,
    const float* __restrict__ ow, float* __restrict__ partial)
{
    __shared__ float ps[256];
    const int kc = blockIdx.x;
    const int b  = blockIdx.y;
    const int t  = threadIdx.x;
    const int j  = kc * 256 + t;
    const int jj = (j < 2048) ? j : j - 2048;
    const int ii = 4 * b + (jj >> 9);
    const int e  = jj & 511;
    float v;
    if (j < 2048) {
        const float* bp = pmean + (size_t)ii * 4 * EE + e;
        v = (bp[0] + bp[512] + bp[1024] + bp[1536]) * (1.0f / 512.0f);
    } else {
        const float* bp = pmax + (size_t)ii * 4 * EE + e;
        v = fmaxf(fmaxf(bp[0], bp[512]), fmaxf(bp[1024], bp[1536]));
    }
    ps[t] = v;
    __syncthreads();
    f32x4 acc = {0.f, 0.f, 0.f, 0.f};
    const float* wp = ow + (size_t)kc * 256 * 1024 + t * 4;
#pragma unroll 8
    for (int q = 0; q < 256; ++q) {
        f32x4 w4 = *(const f32x4*)(wp + (size_t)q * 1024);
        float p = ps[q];
        acc[0] = fmaf(p, w4[0], acc[0]);
        acc[1] = fmaf(p, w4[1], acc[1]);
        acc[2] = fmaf(p, w4[2], acc[2]);
        acc[3] = fmaf(p, w4[3], acc[3]);
    }
    *(f32x4*)(partial + ((size_t)kc * 32 + b) * 1024 + t * 4) = acc;
}

// ---------------------------------------------------------------------------
// K5b: final reduce over 16 K-chunks + bias + relu.
// ---------------------------------------------------------------------------
__global__ __launch_bounds__(256) void k_out_final(
    const float* __restrict__ partial, const float* __restrict__ ob,
    float* __restrict__ out)
{
    const int idx = blockIdx.x * 256 + threadIdx.x;
    const int b = idx >> 10, o = idx & 1023;
    float s = ob[o];
#pragma unroll
    for (int kc = 0; kc < 16; ++kc)
        s += partial[((size_t)kc * 32 + b) * 1024 + o];
    out[idx] = fmaxf(s, 0.f);
}

// ---------------------------------------------------------------------------
extern "C" void kernel_launch(void* const* d_in, const int* in_sizes, int n_in,
                              void* d_out, int out_size, void* d_ws, size_t ws_size,
                              hipStream_t stream)
{
    const float* x1     = (const float*)d_in[0];
    const float* x2     = (const float*)d_in[1];
    const int*   x1_len = (const int*)d_in[2];
    const int*   x2_len = (const int*)d_in[3];
    const float* fw     = (const float*)d_in[4];
    const float* fb     = (const float*)d_in[5];
    const float* ow     = (const float*)d_in[6];
    const float* ob     = (const float*)d_in[7];

    float* out  = (float*)d_out;                  // [32, 1024]
    float* attn = out + (size_t)BATCH * 1024;     // [128, 512, 512] f32

    // workspace layout (~341 MB)
    char* wp = (char*)d_ws;
    unsigned short* x1bf   = (unsigned short*)wp; wp += (size_t)BATCH * LL * EE * 2;
    unsigned short* x2bf   = (unsigned short*)wp; wp += (size_t)NB * LL * EE * 2;
    unsigned short* x2t    = (unsigned short*)wp; wp += (size_t)NB * LL * EE * 2;
    unsigned short* attnbf = (unsigned short*)wp; wp += (size_t)NB * LL * LL * 2;
    unsigned short* Cbuf   = (unsigned short*)wp; wp += (size_t)NB * LL * 1024 * 2;
    unsigned short* fwt    = (unsigned short*)wp; wp += (size_t)EE * 1024 * 2;
    float* pmean   = (float*)wp; wp += (size_t)NB * 4 * EE * 4;
    float* pmax    = (float*)wp; wp += (size_t)NB * 4 * EE * 4;
    float* partial = (float*)wp; wp += (size_t)16 * BATCH * 1024 * 4;

    k_cvt_x1<<<dim3(BATCH * LL * EE / 4 / 256), 256, 0, stream>>>(x1, x1bf);
    k_cvt_x2<<<dim3(8, 8, NB), 256, 0, stream>>>(x2, x2bf, x2t);
    k_cvt_fw<<<dim3(8, 16), 256, 0, stream>>>(fw, fwt);
    k_scores_mfma<<<dim3(128, 16), 256, 0, stream>>>(x1bf, x2bf, x1_len, x2_len, attn);
    k_softmax<<<dim3(NB * LL / 4), 256, 0, stream>>>(attn, attnbf);
    k_pv_mfma<<<dim3(128, 16), 256, 0, stream>>>(attnbf, x2t, x1bf, Cbuf);
    k_fuse_mfma<<<dim3(128, 16), 256, 0, stream>>>(Cbuf, fwt, fb, pmean, pmax);
    k_out_split<<<dim3(16, BATCH), 256, 0, stream>>>(pmean, pmax, ow, partial);
    k_out_final<<<dim3(BATCH * 1024 / 256), 256, 0, stream>>>(partial, ob, out);
}

// Round 2
// 578.544 us; speedup vs baseline: 1.1395x; 1.1010x over previous
//
#include <hip/hip_runtime.h>
#include <cstddef>

// Problem constants (reference: B=32, NDOC=4, L=512, E=512)
#define BATCH 32
#define NB    128
#define LL    512
#define EE    512
#define SCALE 0.044194173824159216f
#define NEG_INF -1e9f

typedef __attribute__((ext_vector_type(4))) float f32x4;
typedef __attribute__((ext_vector_type(8))) short s16x8;          // 8 bf16 (4 VGPRs) MFMA frag
typedef __attribute__((ext_vector_type(4))) unsigned short u16x4;

__device__ __forceinline__ unsigned short f2b(float f) {          // f32 -> bf16 RNE
    unsigned u = __float_as_uint(f);
    u += 0x7FFFu + ((u >> 16) & 1u);
    return (unsigned short)(u >> 16);
}
__device__ __forceinline__ float b2f(unsigned short h) {
    return __uint_as_float(((unsigned)h) << 16);
}

// async global->LDS, 16B per lane. LDS dest = wave-uniform base + lane*16.
__device__ __forceinline__ void gld_lds16(const unsigned short* g, unsigned short* l) {
    __builtin_amdgcn_global_load_lds(
        (const __attribute__((address_space(1))) void*)g,
        (__attribute__((address_space(3))) void*)l, 16, 0, 0);
}

// ---------------------------------------------------------------------------
// Converters: x1 -> bf16; x2 -> bf16 (row) + bf16 transposed; fw -> fw^T bf16
// ---------------------------------------------------------------------------
__global__ __launch_bounds__(256) void k_cvt_x1(
    const float* __restrict__ x1, unsigned short* __restrict__ x1bf)
{
    const size_t idx = (size_t)blockIdx.x * 256 + threadIdx.x;
    f32x4 v = *(const f32x4*)(x1 + idx * 4);
    u16x4 o = { f2b(v[0]), f2b(v[1]), f2b(v[2]), f2b(v[3]) };
    *(u16x4*)(x1bf + idx * 4) = o;
}

__global__ __launch_bounds__(256) void k_cvt_x2(
    const float* __restrict__ x2,
    unsigned short* __restrict__ x2bf, unsigned short* __restrict__ x2t)
{
    __shared__ float T[64][65];
    const int i = blockIdx.z, kb = blockIdx.y * 64, eb = blockIdx.x * 64;
    const float* src = x2 + (size_t)i * LL * EE;
    unsigned short* db = x2bf + (size_t)i * LL * EE;
    unsigned short* dt = x2t  + (size_t)i * LL * EE;
    const int t = threadIdx.x, r16 = t >> 4, c4 = (t & 15) * 4;
#pragma unroll
    for (int p = 0; p < 4; ++p) {
        int row = p * 16 + r16;
        f32x4 v = *(const f32x4*)(src + (size_t)(kb + row) * EE + eb + c4);
        T[row][c4] = v[0]; T[row][c4+1] = v[1]; T[row][c4+2] = v[2]; T[row][c4+3] = v[3];
        u16x4 o = { f2b(v[0]), f2b(v[1]), f2b(v[2]), f2b(v[3]) };
        *(u16x4*)(db + (size_t)(kb + row) * EE + eb + c4) = o;
    }
    __syncthreads();
#pragma unroll
    for (int p = 0; p < 4; ++p) {
        int erow = p * 16 + r16;
        u16x4 o = { f2b(T[c4][erow]), f2b(T[c4+1][erow]),
                    f2b(T[c4+2][erow]), f2b(T[c4+3][erow]) };
        *(u16x4*)(dt + (size_t)(eb + erow) * LL + kb + c4) = o;   // dt[e][k]=src[k][e]
    }
}

// fw [1024][512] -> fwt[e][j'] bf16 with K-interleave j' = (j<512) ? 2j : 2(j-512)+1
// (matches Cbuf's interleaved [diff,prod] pair layout; GEMM result invariant).
__global__ __launch_bounds__(256) void k_cvt_fw(
    const float* __restrict__ fw, unsigned short* __restrict__ fwt)
{
    __shared__ float T[64][65];
    const int jb = blockIdx.y * 64, eb = blockIdx.x * 64;
    const int t = threadIdx.x, r16 = t >> 4, c4 = (t & 15) * 4;
#pragma unroll
    for (int p = 0; p < 4; ++p) {
        int row = p * 16 + r16;
        f32x4 v = *(const f32x4*)(fw + (size_t)(jb + row) * EE + eb + c4);
        T[row][c4] = v[0]; T[row][c4+1] = v[1]; T[row][c4+2] = v[2]; T[row][c4+3] = v[3];
    }
    __syncthreads();
#pragma unroll
    for (int p = 0; p < 4; ++p) {
        int erow = p * 16 + r16;
#pragma unroll
        for (int k = 0; k < 4; ++k) {
            int jold = jb + c4 + k;
            int jn = (jold < 512) ? (2 * jold) : (2 * (jold - 512) + 1);
            fwt[(size_t)(eb + erow) * 1024 + jn] = f2b(T[c4 + k][erow]);
        }
    }
}

// ---------------------------------------------------------------------------
// K1 (fused): scores GEMM -> in-block softmax -> PV GEMM.
// One block = one batch i x 128 q-rows x full k-range (512).
//   Phase 1: scores = mask(x1 @ x2^T * SCALE); 16 waves as 2x8 (64l x 64k each).
//   Softmax: full row owned by the block; 16-lane shuffle + 8-way LDS reduce.
//            Writes final attn f32 (required output) + P bf16 into LDS
//            (XOR-swizzled byte^=(l&7)<<4 to kill 16-way ds_read conflicts).
//   Phase 2: x1_att = P @ x2t; A straight from LDS, B staged per e-half.
// LDS: region1 128KB = scores staging (40KB) then P[128][512]; region2 16KB =
//      softmax reduce arrays then PV B-stage. Time-disjoint via barriers.
// ---------------------------------------------------------------------------
__global__ __launch_bounds__(1024, 4) void k_attn(
    const unsigned short* __restrict__ x1bf,
    const unsigned short* __restrict__ x2bf,
    const unsigned short* __restrict__ x2t,
    const int* __restrict__ x1_len, const int* __restrict__ x2_len,
    float* __restrict__ attn, unsigned short* __restrict__ Cbuf)
{
    __shared__ __align__(16) char smem[147456];                 // 144 KB
    unsigned short* Ast = (unsigned short*)smem;                // [128][32]
    unsigned short* Bst = (unsigned short*)(smem + 8192);       // [512][32]
    // P lives at smem[0..128K), swizzled; addressed via byte offsets.
    unsigned short* Bpv = (unsigned short*)(smem + 131072);     // [256][32]
    float* rowred = (float*)(smem + 131072);                    // [8][128]
    float* rowst  = (float*)(smem + 131072 + 4096);             // [128]

    const int i  = blockIdx.x;
    const int q0 = blockIdx.y * 128;
    const unsigned short* Ag = x1bf + (size_t)(i & 31) * LL * EE;
    const unsigned short* Bg = x2bf + (size_t)i * LL * EE;
    const unsigned short* Vg = x2t  + (size_t)i * LL * EE;
    const int t = threadIdx.x, lane = t & 63;
    const int w = t >> 6;
    const int m = lane & 15, quad = lane >> 4;
    const int lrow = lane >> 2, lcol = (lane & 3) * 8;
    const int wrow = w >> 3, wcol = w & 7;                      // scores: 2x8 waves

    f32x4 acc[4][4];
#pragma unroll
    for (int r = 0; r < 4; ++r)
#pragma unroll
        for (int c = 0; c < 4; ++c) acc[r][c] = (f32x4){0.f, 0.f, 0.f, 0.f};

    // ---- Phase 1: scores GEMM over e ----
    for (int e0 = 0; e0 < EE; e0 += 32) {
        if (w < 8)
            gld_lds16(Ag + (size_t)(q0 + w * 16 + lrow) * EE + e0 + lcol, &Ast[w * 512]);
        gld_lds16(Bg + (size_t)((2 * w) * 16 + lrow) * EE + e0 + lcol, &Bst[(2 * w) * 512]);
        gld_lds16(Bg + (size_t)((2 * w + 1) * 16 + lrow) * EE + e0 + lcol, &Bst[(2 * w + 1) * 512]);
        __syncthreads();
        s16x8 af[4], bfr[4];
#pragma unroll
        for (int rt = 0; rt < 4; ++rt)
            af[rt] = *(const s16x8*)&Ast[(wrow * 64 + rt * 16 + m) * 32 + quad * 8];
#pragma unroll
        for (int ct = 0; ct < 4; ++ct)
            bfr[ct] = *(const s16x8*)&Bst[(wcol * 64 + ct * 16 + m) * 32 + quad * 8];
#pragma unroll
        for (int rt = 0; rt < 4; ++rt)
#pragma unroll
            for (int ct = 0; ct < 4; ++ct)
                acc[rt][ct] = __builtin_amdgcn_mfma_f32_16x16x32_bf16(
                    af[rt], bfr[ct], acc[rt][ct], 0, 0, 0);
        __syncthreads();
    }

    const int qlen = x1_len[i & 31];
    const int klen = x2_len[i];

    // ---- mask + scale in place ----
#pragma unroll
    for (int rt = 0; rt < 4; ++rt)
#pragma unroll
        for (int reg = 0; reg < 4; ++reg) {
            const int l = q0 + wrow * 64 + rt * 16 + quad * 4 + reg;
            const bool qok = l < qlen;
#pragma unroll
            for (int ct = 0; ct < 4; ++ct) {
                const int k = wcol * 64 + ct * 16 + m;
                acc[rt][ct][reg] = (qok && k < klen) ? acc[rt][ct][reg] * SCALE : NEG_INF;
            }
        }

    // ---- row max: per-wave 64-col partial -> LDS -> 8-way reduce ----
#pragma unroll
    for (int rt = 0; rt < 4; ++rt)
#pragma unroll
        for (int reg = 0; reg < 4; ++reg) {
            float v = fmaxf(fmaxf(acc[rt][0][reg], acc[rt][1][reg]),
                            fmaxf(acc[rt][2][reg], acc[rt][3][reg]));
            v = fmaxf(v, __shfl_xor(v, 1));
            v = fmaxf(v, __shfl_xor(v, 2));
            v = fmaxf(v, __shfl_xor(v, 4));
            v = fmaxf(v, __shfl_xor(v, 8));
            if (m == 0)
                rowred[wcol * 128 + wrow * 64 + rt * 16 + quad * 4 + reg] = v;
        }
    __syncthreads();
    if (t < 128) {
        float mx = rowred[t];
#pragma unroll
        for (int c = 1; c < 8; ++c) mx = fmaxf(mx, rowred[c * 128 + t]);
        rowst[t] = mx;
    }
    __syncthreads();

    // ---- exp + row sum ----
#pragma unroll
    for (int rt = 0; rt < 4; ++rt)
#pragma unroll
        for (int reg = 0; reg < 4; ++reg) {
            const int lloc = wrow * 64 + rt * 16 + quad * 4 + reg;
            const float mx = rowst[lloc];
            float s = 0.f;
#pragma unroll
            for (int ct = 0; ct < 4; ++ct) {
                float p = __expf(acc[rt][ct][reg] - mx);
                acc[rt][ct][reg] = p;
                s += p;
            }
            s += __shfl_xor(s, 1);
            s += __shfl_xor(s, 2);
            s += __shfl_xor(s, 4);
            s += __shfl_xor(s, 8);
            if (m == 0) rowred[wcol * 128 + lloc] = s;
        }
    __syncthreads();
    if (t < 128) {
        float s = 0.f;
#pragma unroll
        for (int c = 0; c < 8; ++c) s += rowred[c * 128 + t];
        rowst[t] = 1.0f / s;
    }
    __syncthreads();

    // ---- normalize: write attn f32 (output) + P bf16 (LDS, swizzled) ----
    float* op = attn + (size_t)i * LL * LL;
#pragma unroll
    for (int rt = 0; rt < 4; ++rt)
#pragma unroll
        for (int reg = 0; reg < 4; ++reg) {
            const int lloc = wrow * 64 + rt * 16 + quad * 4 + reg;
            const float inv = rowst[lloc];
#pragma unroll
            for (int ct = 0; ct < 4; ++ct) {
                const int k = wcol * 64 + ct * 16 + m;
                float p = acc[rt][ct][reg] * inv;
                op[(size_t)(q0 + lloc) * LL + k] = p;
                unsigned off = (unsigned)(lloc * 1024 + k * 2) ^ (unsigned)((lloc & 7) << 4);
                *(unsigned short*)(smem + off) = f2b(p);
            }
        }
    __syncthreads();                                           // P complete

    // ---- Phase 2: PV GEMM, two e-halves of 256 ----
    const int pwr = w >> 2, pwc = w & 3;                       // PV: 4x4 waves
    unsigned short* Cb = Cbuf + (size_t)i * LL * 1024;
#pragma unroll
    for (int eh = 0; eh < 2; ++eh) {
        f32x4 acc2[2][4];
#pragma unroll
        for (int r = 0; r < 2; ++r)
#pragma unroll
            for (int c = 0; c < 4; ++c) acc2[r][c] = (f32x4){0.f, 0.f, 0.f, 0.f};

        for (int k0 = 0; k0 < LL; k0 += 32) {
            gld_lds16(Vg + (size_t)(eh * 256 + w * 16 + lrow) * LL + k0 + lcol, &Bpv[w * 512]);
            __syncthreads();
            s16x8 paf[2], pbf[4];
#pragma unroll
            for (int rt = 0; rt < 2; ++rt) {
                const int lr = pwr * 32 + rt * 16 + m;
                unsigned off = (unsigned)(lr * 1024 + (k0 + quad * 8) * 2)
                               ^ (unsigned)((lr & 7) << 4);
                paf[rt] = *(const s16x8*)(smem + off);
            }
#pragma unroll
            for (int ct = 0; ct < 4; ++ct)
                pbf[ct] = *(const s16x8*)&Bpv[(pwc * 64 + ct * 16 + m) * 32 + quad * 8];
#pragma unroll
            for (int rt = 0; rt < 2; ++rt)
#pragma unroll
                for (int ct = 0; ct < 4; ++ct)
                    acc2[rt][ct] = __builtin_amdgcn_mfma_f32_16x16x32_bf16(
                        paf[rt], pbf[ct], acc2[rt][ct], 0, 0, 0);
            __syncthreads();
        }

        // epilogue: Cbuf[l][2e]=x1-att, [2e+1]=x1*att
#pragma unroll
        for (int rt = 0; rt < 2; ++rt)
#pragma unroll
            for (int reg = 0; reg < 4; ++reg) {
                const int l = q0 + pwr * 32 + rt * 16 + quad * 4 + reg;
#pragma unroll
                for (int ct = 0; ct < 4; ++ct) {
                    const int e = eh * 256 + pwc * 64 + ct * 16 + m;
                    float att = acc2[rt][ct][reg];
                    float xv  = b2f(Ag[(size_t)l * EE + e]);
                    unsigned pr = (unsigned)f2b(xv - att) | ((unsigned)f2b(xv * att) << 16);
                    *(unsigned*)(Cb + (size_t)l * 1024 + 2 * e) = pr;
                }
            }
    }
}

// ---------------------------------------------------------------------------
// K4: fus = relu(Cbuf @ fw + b) with per-l-tile mean/max pooling partials.
// A rows are the interleaved Cbuf layout; B (fwt) carries the same K-perm.
// ---------------------------------------------------------------------------
__global__ __launch_bounds__(256) void k_fuse_mfma(
    const unsigned short* __restrict__ Cbuf,
    const unsigned short* __restrict__ fwt,
    const float* __restrict__ fb,
    float* __restrict__ pmean, float* __restrict__ pmax)
{
    __shared__ unsigned short Al[128 * 32];
    __shared__ unsigned short Bl[128 * 32];
    __shared__ float psum[2][128];
    __shared__ float pmx[2][128];
    const int i  = blockIdx.x;
    const int lt = blockIdx.y >> 2;
    const int e0 = (blockIdx.y & 3) * 128;
    const unsigned short* Ab = Cbuf + ((size_t)i * LL + lt * 128) * 1024;
    const int t = threadIdx.x, lane = t & 63;
    const int w = t >> 6, wrow = w >> 1, wcol = w & 1;
    const int m = lane & 15, quad = lane >> 4;
    const int lrow = lane >> 2, lcol = (lane & 3) * 8;

    float bias[4];
#pragma unroll
    for (int ct = 0; ct < 4; ++ct) bias[ct] = fb[e0 + wcol * 64 + ct * 16 + m];
    float csum[4] = {0.f, 0.f, 0.f, 0.f};
    float cmax[4] = {-3e38f, -3e38f, -3e38f, -3e38f};

    f32x4 acc[4][4];
#pragma unroll
    for (int r = 0; r < 4; ++r)
#pragma unroll
        for (int c = 0; c < 4; ++c) acc[r][c] = (f32x4){0.f, 0.f, 0.f, 0.f};

    for (int j0 = 0; j0 < 1024; j0 += 32) {
#pragma unroll
        for (int c = 0; c < 2; ++c) {
            const int s = c * 4 + w;
            gld_lds16(Ab + (size_t)(s * 16 + lrow) * 1024 + j0 + lcol, &Al[s * 512]);
            gld_lds16(fwt + (size_t)(e0 + s * 16 + lrow) * 1024 + j0 + lcol, &Bl[s * 512]);
        }
        __syncthreads();
        s16x8 af[4], bfr[4];
#pragma unroll
        for (int rt = 0; rt < 4; ++rt)
            af[rt] = *(const s16x8*)&Al[(wrow * 64 + rt * 16 + m) * 32 + quad * 8];
#pragma unroll
        for (int ct = 0; ct < 4; ++ct)
            bfr[ct] = *(const s16x8*)&Bl[(wcol * 64 + ct * 16 + m) * 32 + quad * 8];
#pragma unroll
        for (int rt = 0; rt < 4; ++rt)
#pragma unroll
            for (int ct = 0; ct < 4; ++ct)
                acc[rt][ct] = __builtin_amdgcn_mfma_f32_16x16x32_bf16(
                    af[rt], bfr[ct], acc[rt][ct], 0, 0, 0);
        __syncthreads();
    }
#pragma unroll
    for (int rt = 0; rt < 4; ++rt)
#pragma unroll
        for (int reg = 0; reg < 4; ++reg)
#pragma unroll
            for (int ct = 0; ct < 4; ++ct) {
                float f = fmaxf(acc[rt][ct][reg] + bias[ct], 0.f);
                csum[ct] += f;
                cmax[ct] = fmaxf(cmax[ct], f);
            }
#pragma unroll
    for (int ct = 0; ct < 4; ++ct) {
        csum[ct] += __shfl_xor(csum[ct], 16);
        csum[ct] += __shfl_xor(csum[ct], 32);
        cmax[ct] = fmaxf(cmax[ct], __shfl_xor(cmax[ct], 16));
        cmax[ct] = fmaxf(cmax[ct], __shfl_xor(cmax[ct], 32));
    }
    if (quad == 0) {
#pragma unroll
        for (int ct = 0; ct < 4; ++ct) {
            psum[wrow][wcol * 64 + ct * 16 + m] = csum[ct];
            pmx[wrow][wcol * 64 + ct * 16 + m] = cmax[ct];
        }
    }
    __syncthreads();
    if (t < 128) {
        float s  = psum[0][t] + psum[1][t];
        float mx = fmaxf(pmx[0][t], pmx[1][t]);
        pmean[((size_t)i * 4 + lt) * EE + e0 + t] = s;     // raw sum over 128 l's
        pmax[((size_t)i * 4 + lt) * EE + e0 + t]  = mx;
    }
}

// ---------------------------------------------------------------------------
// K5a: split-K partial GEMM for the output head; reduces the 4 l-tile pooling
// partials inline while loading the pooled vector.
// ---------------------------------------------------------------------------
__global__ __launch_bounds__(256) void k_out_split(
    const float* __restrict__ pmean, const float* __restrict__ pmax,
    const float* __restrict__ ow, float* __restrict__ partial)
{
    __shared__ float ps[256];
    const int kc = blockIdx.x;
    const int b  = blockIdx.y;
    const int t  = threadIdx.x;
    const int j  = kc * 256 + t;
    const int jj = (j < 2048) ? j : j - 2048;
    const int ii = 4 * b + (jj >> 9);
    const int e  = jj & 511;
    float v;
    if (j < 2048) {
        const float* bp = pmean + (size_t)ii * 4 * EE + e;
        v = (bp[0] + bp[512] + bp[1024] + bp[1536]) * (1.0f / 512.0f);
    } else {
        const float* bp = pmax + (size_t)ii * 4 * EE + e;
        v = fmaxf(fmaxf(bp[0], bp[512]), fmaxf(bp[1024], bp[1536]));
    }
    ps[t] = v;
    __syncthreads();
    f32x4 acc = {0.f, 0.f, 0.f, 0.f};
    const float* wp = ow + (size_t)kc * 256 * 1024 + t * 4;
#pragma unroll 8
    for (int q = 0; q < 256; ++q) {
        f32x4 w4 = *(const f32x4*)(wp + (size_t)q * 1024);
        float p = ps[q];
        acc[0] = fmaf(p, w4[0], acc[0]);
        acc[1] = fmaf(p, w4[1], acc[1]);
        acc[2] = fmaf(p, w4[2], acc[2]);
        acc[3] = fmaf(p, w4[3], acc[3]);
    }
    *(f32x4*)(partial + ((size_t)kc * 32 + b) * 1024 + t * 4) = acc;
}

// ---------------------------------------------------------------------------
// K5b: final reduce over 16 K-chunks + bias + relu.
// ---------------------------------------------------------------------------
__global__ __launch_bounds__(256) void k_out_final(
    const float* __restrict__ partial, const float* __restrict__ ob,
    float* __restrict__ out)
{
    const int idx = blockIdx.x * 256 + threadIdx.x;
    const int b = idx >> 10, o = idx & 1023;
    float s = ob[o];
#pragma unroll
    for (int kc = 0; kc < 16; ++kc)
        s += partial[((size_t)kc * 32 + b) * 1024 + o];
    out[idx] = fmaxf(s, 0.f);
}

// ---------------------------------------------------------------------------
extern "C" void kernel_launch(void* const* d_in, const int* in_sizes, int n_in,
                              void* d_out, int out_size, void* d_ws, size_t ws_size,
                              hipStream_t stream)
{
    const float* x1     = (const float*)d_in[0];
    const float* x2     = (const float*)d_in[1];
    const int*   x1_len = (const int*)d_in[2];
    const int*   x2_len = (const int*)d_in[3];
    const float* fw     = (const float*)d_in[4];
    const float* fb     = (const float*)d_in[5];
    const float* ow     = (const float*)d_in[6];
    const float* ob     = (const float*)d_in[7];

    float* out  = (float*)d_out;                  // [32, 1024]
    float* attn = out + (size_t)BATCH * 1024;     // [128, 512, 512] f32

    // workspace layout (~275 MB)
    char* wp = (char*)d_ws;
    unsigned short* x1bf   = (unsigned short*)wp; wp += (size_t)BATCH * LL * EE * 2;
    unsigned short* x2bf   = (unsigned short*)wp; wp += (size_t)NB * LL * EE * 2;
    unsigned short* x2t    = (unsigned short*)wp; wp += (size_t)NB * LL * EE * 2;
    unsigned short* Cbuf   = (unsigned short*)wp; wp += (size_t)NB * LL * 1024 * 2;
    unsigned short* fwt    = (unsigned short*)wp; wp += (size_t)EE * 1024 * 2;
    float* pmean   = (float*)wp; wp += (size_t)NB * 4 * EE * 4;
    float* pmax    = (float*)wp; wp += (size_t)NB * 4 * EE * 4;
    float* partial = (float*)wp; wp += (size_t)16 * BATCH * 1024 * 4;

    k_cvt_x1<<<dim3(BATCH * LL * EE / 4 / 256), 256, 0, stream>>>(x1, x1bf);
    k_cvt_x2<<<dim3(8, 8, NB), 256, 0, stream>>>(x2, x2bf, x2t);
    k_cvt_fw<<<dim3(8, 16), 256, 0, stream>>>(fw, fwt);
    k_attn<<<dim3(128, 4), 1024, 0, stream>>>(x1bf, x2bf, x2t, x1_len, x2_len, attn, Cbuf);
    k_fuse_mfma<<<dim3(128, 16), 256, 0, stream>>>(Cbuf, fwt, fb, pmean, pmax);
    k_out_split<<<dim3(16, BATCH), 256, 0, stream>>>(pmean, pmax, ow, partial);
    k_out_final<<<dim3(BATCH * 1024 / 256), 256, 0, stream>>>(partial, ob, out);
}